// Round 4
// baseline (500680.615 us; speedup 1.0000x reference)
//
#include <hip/hip_runtime.h>
#include <math.h>

#define B_TOT 2048
#define T_LEN 1024
#define HID   512
#define CH    9
#define CONDK 272            // 128 + 128 + 16
#define ROWS  8              // batch rows per workgroup
#define NWG   (B_TOT/ROWS)   // 256 = 1 WG per CU
#define NTHR  1024           // 2 threads per hidden unit: batch-half split (NOT K-split)

// ws layout (floats): packed float3 weight panels, k-major
// W1p[k][u][{r,z,n}], k in [0,530): k<512 = h-part (w_hh1), k>=512 = x-part (w_ih1)
// W2p[k][u][{r,z,n}], k in [0,1024): k<512 = h2-part (w_hh2), k>=512 = h1-part (w_ih2)
#define K1TOT (HID + 18)
#define K2TOT (2*HID)
#define SZ_W1P  (K1TOT * HID * 3)
#define SZ_W2P  (K2TOT * HID * 3)
#define SZ_WHT  (CONDK * HID)
#define OFF_W1P 0
#define OFF_W2P (OFF_W1P + SZ_W1P)
#define OFF_WHT (OFF_W2P + SZ_W2P)

__global__ void prep_kernel(const float* __restrict__ w_ih1, const float* __restrict__ w_hh1,
                            const float* __restrict__ w_ih2, const float* __restrict__ w_hh2,
                            const float* __restrict__ W_h, float* __restrict__ ws)
{
    int i = blockIdx.x * blockDim.x + threadIdx.x;
    const int total = SZ_W1P + SZ_W2P + SZ_WHT;
    if (i >= total) return;
    if (i < SZ_W1P) {
        int g = i % 3, rest = i / 3;
        int u = rest % HID, k = rest / HID;
        ws[OFF_W1P + i] = (k < HID) ? w_hh1[(size_t)(g*HID + u)*HID + k]
                                    : w_ih1[(size_t)(g*HID + u)*18  + (k - HID)];
    } else if (i < SZ_W1P + SZ_W2P) {
        int j = i - SZ_W1P;
        int g = j % 3, rest = j / 3;
        int u = rest % HID, k = rest / HID;
        ws[OFF_W2P + j] = (k < HID) ? w_hh2[(size_t)(g*HID + u)*HID + k]
                                    : w_ih2[(size_t)(g*HID + u)*HID + (k - HID)];
    } else {
        int j = i - SZ_W1P - SZ_W2P;
        int k = j / HID, u = j % HID;
        ws[OFF_WHT + j] = W_h[(size_t)u*CONDK + k];
    }
}

__device__ __forceinline__ float sigmf(float x) { return 1.0f / (1.0f + expf(-x)); }

__global__ __launch_bounds__(NTHR, 4)
void note_decoder_kernel(const float* __restrict__ z, const float* __restrict__ se,
                         const float* __restrict__ skel, const float* __restrict__ cond,
                         const float* __restrict__ rnd,
                         const float* __restrict__ b_h,
                         const float* __restrict__ b_ih1, const float* __restrict__ b_hh1,
                         const float* __restrict__ b_ih2, const float* __restrict__ b_hh2,
                         const float* __restrict__ W_out, const float* __restrict__ b_out,
                         const float* __restrict__ ws,
                         float* __restrict__ out)
{
    // hs[0] = h1, hs[1] = h2; k-major [k][b]
    __shared__ float hs[2][HID][ROWS];
    __shared__ float xf[2*CH][ROWS];      // x = [out(9) | skel(9)], k-major
    __shared__ float wouts[HID][CH];

    const float* __restrict__ W1p = ws + OFF_W1P;
    const float* __restrict__ W2p = ws + OFF_W2P;
    const float* __restrict__ Wht = ws + OFF_WHT;

    const int tid  = threadIdx.x;
    const int half = tid & 1;              // batch-half: rows [half*4, half*4+4)
    const int u    = tid >> 1;             // hidden unit owned by this thread
    const int b0   = half * 4;
    const int row0 = blockIdx.x * ROWS;

    // stage W_out as [u][c]
    for (int i = tid; i < CH*HID; i += NTHR) {
        int c = i / HID, uu = i % HID;
        wouts[uu][c] = W_out[i];
    }
    // stage zc = [z | skel_encoded | cond] into hs[1] scratch, k-major (pure copy)
    for (int i = tid; i < ROWS*CONDK; i += NTHR) {
        int b = i / CONDK, k = i % CONDK;
        float v;
        if (k < 128)       v = z[(row0 + b)*128 + k];
        else if (k < 256)  v = se[(row0 + b)*128 + (k - 128)];
        else               v = cond[(row0 + b)*16 + (k - 256)];
        hs[1][k][b] = v;
    }
    if (tid < ROWS*CH) xf[tid % CH][tid / CH] = 0.0f;   // out0 = 0 (xf[c][b])
    __syncthreads();

    // h1_0 = tanh(zc @ W_h^T + b_h): full K per thread (sequential, R2 order), 4 rows
    {
        float acc[4] = {0.f, 0.f, 0.f, 0.f};
        #pragma unroll 4
        for (int k = 0; k < CONDK; ++k) {
            float w = Wht[k*HID + u];
            float4 a = *(const float4*)&hs[1][k][b0];
            acc[0] = fmaf(a.x, w, acc[0]);
            acc[1] = fmaf(a.y, w, acc[1]);
            acc[2] = fmaf(a.z, w, acc[2]);
            acc[3] = fmaf(a.w, w, acc[3]);
        }
        float bh = b_h[u];
        __syncthreads();   // zc reads done (hs[1] will be overwritten at t==0)
        #pragma unroll
        for (int j = 0; j < 4; ++j) acc[j] = tanhf(acc[j] + bh);
        *(float4*)&hs[0][u][b0] = make_float4(acc[0], acc[1], acc[2], acc[3]);
    }

    // hoisted biases (per unit u)
    const float br1 = b_ih1[u]         + b_hh1[u];
    const float bz1 = b_ih1[HID + u]   + b_hh1[HID + u];
    const float bi1 = b_ih1[2*HID + u];
    const float bn1 = b_hh1[2*HID + u];
    const float br2 = b_ih2[u]         + b_hh2[u];
    const float bz2 = b_ih2[HID + u]   + b_hh2[HID + u];
    const float bi2 = b_ih2[2*HID + u];
    const float bn2 = b_hh2[2*HID + u];

    const int wv = tid >> 6, ln = tid & 63;

    for (int t = 0; t < T_LEN; ++t) {
        // stage skel half of x; feedback xf[0..8] from prev out_fc
        if (tid < ROWS*CH) {
            int b = tid / CH, c = tid % CH;
            xf[CH + c][b] = skel[((size_t)(row0 + b)*T_LEN + t)*CH + c];
        }
        __syncthreads();                                   // A: xf + h1_0/hs ready

        // ---- GRU1: full K sequential per thread, 4 batch rows ----
        float ar[4], az[4], ai[4], ah[4];
        #pragma unroll
        for (int j = 0; j < 4; ++j) { ar[j]=0.f; az[j]=0.f; ai[j]=0.f; ah[j]=0.f; }
        #pragma unroll 4
        for (int k = 0; k < HID; ++k) {                    // h-part -> r,z,hn
            float3 w = *(const float3*)(W1p + ((size_t)k*HID + u)*3);
            float4 a = *(const float4*)&hs[0][k][b0];
            ar[0]=fmaf(a.x,w.x,ar[0]); az[0]=fmaf(a.x,w.y,az[0]); ah[0]=fmaf(a.x,w.z,ah[0]);
            ar[1]=fmaf(a.y,w.x,ar[1]); az[1]=fmaf(a.y,w.y,az[1]); ah[1]=fmaf(a.y,w.z,ah[1]);
            ar[2]=fmaf(a.z,w.x,ar[2]); az[2]=fmaf(a.z,w.y,az[2]); ah[2]=fmaf(a.z,w.z,ah[2]);
            ar[3]=fmaf(a.w,w.x,ar[3]); az[3]=fmaf(a.w,w.y,az[3]); ah[3]=fmaf(a.w,w.z,ah[3]);
        }
        #pragma unroll
        for (int i = 0; i < 18; ++i) {                     // x-part -> r,z,in
            float3 w = *(const float3*)(W1p + ((size_t)(HID + i)*HID + u)*3);
            float4 a = *(const float4*)&xf[i][b0];
            ar[0]=fmaf(a.x,w.x,ar[0]); az[0]=fmaf(a.x,w.y,az[0]); ai[0]=fmaf(a.x,w.z,ai[0]);
            ar[1]=fmaf(a.y,w.x,ar[1]); az[1]=fmaf(a.y,w.y,az[1]); ai[1]=fmaf(a.y,w.z,ai[1]);
            ar[2]=fmaf(a.z,w.x,ar[2]); az[2]=fmaf(a.z,w.y,az[2]); ai[2]=fmaf(a.z,w.z,ai[2]);
            ar[3]=fmaf(a.w,w.x,ar[3]); az[3]=fmaf(a.w,w.y,az[3]); ai[3]=fmaf(a.w,w.z,ai[3]);
        }
        float4 p = *(const float4*)&hs[0][u][b0];
        float h1old[4] = {p.x, p.y, p.z, p.w};
        float h1n[4];
        #pragma unroll
        for (int j = 0; j < 4; ++j) {
            float r  = sigmf(ar[j] + br1);
            float zg = sigmf(az[j] + bz1);
            float n  = tanhf(fmaf(r, ah[j] + bn1, ai[j] + bi1));
            h1n[j] = (1.0f - zg)*n + zg*h1old[j];
        }
        __syncthreads();                                   // B: all hs[0] reads done
        *(float4*)&hs[0][u][b0] = make_float4(h1n[0], h1n[1], h1n[2], h1n[3]);
        if (t == 0)                                        // hx[1] = hx[0] at i==0
            *(float4*)&hs[1][u][b0] = make_float4(h1n[0], h1n[1], h1n[2], h1n[3]);
        __syncthreads();                                   // C: new h1 (and h2@t0) visible

        // ---- GRU2: two sequential loops (h2-part, then h1-part) to keep R2's order ----
        #pragma unroll
        for (int j = 0; j < 4; ++j) { ar[j]=0.f; az[j]=0.f; ai[j]=0.f; ah[j]=0.f; }
        #pragma unroll 4
        for (int k = 0; k < HID; ++k) {                    // h2-part -> r,z,hn
            float3 w = *(const float3*)(W2p + ((size_t)k*HID + u)*3);
            float4 a = *(const float4*)&hs[1][k][b0];
            ar[0]=fmaf(a.x,w.x,ar[0]); az[0]=fmaf(a.x,w.y,az[0]); ah[0]=fmaf(a.x,w.z,ah[0]);
            ar[1]=fmaf(a.y,w.x,ar[1]); az[1]=fmaf(a.y,w.y,az[1]); ah[1]=fmaf(a.y,w.z,ah[1]);
            ar[2]=fmaf(a.z,w.x,ar[2]); az[2]=fmaf(a.z,w.y,az[2]); ah[2]=fmaf(a.z,w.z,ah[2]);
            ar[3]=fmaf(a.w,w.x,ar[3]); az[3]=fmaf(a.w,w.y,az[3]); ah[3]=fmaf(a.w,w.z,ah[3]);
        }
        #pragma unroll 4
        for (int k = 0; k < HID; ++k) {                    // h1-part -> r,z,in
            float3 w = *(const float3*)(W2p + ((size_t)(HID + k)*HID + u)*3);
            float4 a = *(const float4*)&hs[0][k][b0];
            ar[0]=fmaf(a.x,w.x,ar[0]); az[0]=fmaf(a.x,w.y,az[0]); ai[0]=fmaf(a.x,w.z,ai[0]);
            ar[1]=fmaf(a.y,w.x,ar[1]); az[1]=fmaf(a.y,w.y,az[1]); ai[1]=fmaf(a.y,w.z,ai[1]);
            ar[2]=fmaf(a.z,w.x,ar[2]); az[2]=fmaf(a.z,w.y,az[2]); ai[2]=fmaf(a.z,w.z,ai[2]);
            ar[3]=fmaf(a.w,w.x,ar[3]); az[3]=fmaf(a.w,w.y,az[3]); ai[3]=fmaf(a.w,w.z,ai[3]);
        }
        float4 q = *(const float4*)&hs[1][u][b0];
        float h2old[4] = {q.x, q.y, q.z, q.w};
        float h2n[4];
        #pragma unroll
        for (int j = 0; j < 4; ++j) {
            float r  = sigmf(ar[j] + br2);
            float zg = sigmf(az[j] + bz2);
            float n  = tanhf(fmaf(r, ah[j] + bn2, ai[j] + bi2));
            h2n[j] = (1.0f - zg)*n + zg*h2old[j];
        }
        __syncthreads();                                   // D: hs reads done
        *(float4*)&hs[1][u][b0] = make_float4(h2n[0], h2n[1], h2n[2], h2n[3]);
        __syncthreads();                                   // E: new h2 visible

        // ---- note = tanh(h2) @ W_out^T + b_out; Bernoulli sample (waves 0-7, R2-exact) ----
        if (tid < 512) {
            float na[CH];
            #pragma unroll
            for (int c = 0; c < CH; ++c) na[c] = 0.0f;
            for (int kk = ln; kk < HID; kk += 64) {
                float th = tanhf(hs[1][kk][wv]);
                #pragma unroll
                for (int c = 0; c < CH; ++c) na[c] = fmaf(th, wouts[kk][c], na[c]);
            }
            #pragma unroll
            for (int c = 0; c < CH; ++c) {
                #pragma unroll
                for (int off = 32; off; off >>= 1)
                    na[c] += __shfl_xor(na[c], off, 64);
            }
            if (ln < CH) {
                int c = ln;
                float note = na[c] + b_out[c];
                float sg = sigmf(note);
                float rv = rnd[((size_t)t*B_TOT + row0 + wv)*CH + c];
                xf[c][wv] = (sg - rv > 0.0f) ? 1.0f : 0.0f;   // feedback bit
                out[((size_t)(row0 + wv)*T_LEN + t)*CH + c] = note;
            }
        }
        __syncthreads();                                   // F: xf feedback visible next iter
    }
}

extern "C" void kernel_launch(void* const* d_in, const int* in_sizes, int n_in,
                              void* d_out, int out_size, void* d_ws, size_t ws_size,
                              hipStream_t stream)
{
    const float* z     = (const float*)d_in[0];
    const float* se    = (const float*)d_in[1];
    const float* skel  = (const float*)d_in[2];
    const float* cond  = (const float*)d_in[3];
    const float* rnd   = (const float*)d_in[4];
    const float* W_h   = (const float*)d_in[5];
    const float* b_h   = (const float*)d_in[6];
    const float* w_ih1 = (const float*)d_in[7];
    const float* w_hh1 = (const float*)d_in[8];
    const float* b_ih1 = (const float*)d_in[9];
    const float* b_hh1 = (const float*)d_in[10];
    const float* w_ih2 = (const float*)d_in[11];
    const float* w_hh2 = (const float*)d_in[12];
    const float* b_ih2 = (const float*)d_in[13];
    const float* b_hh2 = (const float*)d_in[14];
    const float* W_out = (const float*)d_in[15];
    const float* b_out = (const float*)d_in[16];
    float* ws  = (float*)d_ws;
    float* out = (float*)d_out;

    const int total = SZ_W1P + SZ_W2P + SZ_WHT;
    prep_kernel<<<(total + 255)/256, 256, 0, stream>>>(w_ih1, w_hh1, w_ih2, w_hh2, W_h, ws);
    note_decoder_kernel<<<NWG, NTHR, 0, stream>>>(z, se, skel, cond, rnd, b_h,
                                                  b_ih1, b_hh1, b_ih2, b_hh2,
                                                  W_out, b_out, ws, out);
}